// Round 7
// baseline (272.545 us; speedup 1.0000x reference)
//
#include <hip/hip_runtime.h>
#include <hip/hip_bf16.h>

namespace {

typedef float f4 __attribute__((ext_vector_type(4)));
typedef short short8 __attribute__((ext_vector_type(8)));
typedef short short4v __attribute__((ext_vector_type(4)));

constexpr int NTAGS = 64;
constexpr int START_T = 62;
constexpr int STOP_T = 63;
constexpr int Bc = 512;
constexpr int Lc = 512;
constexpr float LOG2E = 1.4426950408889634f;
constexpr int LSTR = 72;  // LDS row stride (bf16 elems): 144B, keeps b128 reads 16B-aligned

__device__ __forceinline__ float wave_max(float v) {
#pragma unroll
  for (int off = 32; off >= 1; off >>= 1)
    v = fmaxf(v, __shfl_xor(v, off, 64));
  return v;
}
__device__ __forceinline__ float wave_sum(float v) {
#pragma unroll
  for (int off = 32; off >= 1; off >>= 1)
    v += __shfl_xor(v, off, 64);
  return v;
}
__device__ __forceinline__ unsigned short f2bf(float x) {
  return __builtin_bit_cast(unsigned short, __float2bfloat16(x));
}
__device__ __forceinline__ float bf2f(unsigned short h) {
  return __uint_as_float(((unsigned)h) << 16);
}

// ---------------------------------------------------------------------------
// Forward scan, MFMA edition. One wave per 16 batches (32 blocks x 64 thr).
// State: v[j,b] = exp(alpha[j,b] - Msum*ln2), bf16, in LDS [16][64] (stride 72).
// Step: D[i,b] = sum_j E[i,j] v[j,b] via 8x mfma_f32_16x16x32_bf16 with
// CONSTANT A fragments (E = exp(trans)); then v' = D * exp2(emit*log2e - d);
// d = exponent of a stale representative element (exact integer Msum).
// A/B share the same K-permutation so the k-layout assumption cancels; C/D
// mapping (col=lane&15, row=4*(lane>>4)+reg) is the HW-verified one.
// ---------------------------------------------------------------------------
__global__ __launch_bounds__(64, 1) void crf_scan(
    const float* __restrict__ inputs,   // [B, L, 64]
    const int* __restrict__ mask,       // [B, L]
    const float* __restrict__ trans,    // [64, 64]
    float* __restrict__ den) {          // [B] logdenominator
  __shared__ unsigned short vlds[16 * LSTR];

  const int lane = threadIdx.x;
  const int q = lane >> 4;   // 0..3
  const int b = lane & 15;   // batch slot (also A-row mi)
  const int bblk = blockIdx.x;
  const int bg = bblk * 16 + b;

  // --- A fragments: A[mt][kt], i = 16mt + (lane&15), k = 32kt + 8q + e ---
  short8 A00, A01, A10, A11, A20, A21, A30, A31;
#define LOADA(mt, dst0, dst1)                                          \
  {                                                                    \
    const float* tp = trans + (16 * (mt) + b) * NTAGS + 8 * q;         \
    short8 x0, x1;                                                     \
    _Pragma("unroll") for (int e = 0; e < 8; ++e) {                    \
      x0[e] = (short)f2bf(__expf(tp[e]));                              \
      x1[e] = (short)f2bf(__expf(tp[32 + e]));                         \
    }                                                                  \
    dst0 = x0;                                                         \
    dst1 = x1;                                                         \
  }
  LOADA(0, A00, A01) LOADA(1, A10, A11) LOADA(2, A20, A21) LOADA(3, A30, A31)

  // --- init v(0) = onehot(START_T) per batch ---
  for (int i = lane; i < 16 * LSTR; i += 64) vlds[i] = 0;
  if (lane < 16) vlds[lane * LSTR + START_T] = 0x3F80;  // bf16 1.0
  __builtin_amdgcn_wave_barrier();

  short8 B0 = *(const short8*)&vlds[LSTR * b + 8 * q];
  short8 B1 = *(const short8*)&vlds[LSTR * b + 32 + 8 * q];

  const float* ep = inputs + (size_t)bg * Lc * NTAGS + 4 * q;
  const int* mp = mask + (size_t)bg * Lc;

  // emit prefetch, 4 steps deep; [slot][mt], all indices compile-time
  float4 pf[4][4];
#pragma unroll
  for (int s = 0; s < 4; ++s)
#pragma unroll
    for (int mt = 0; mt < 4; ++mt)
      pf[s][mt] = *(const float4*)(ep + (size_t)s * NTAGS + 16 * mt);

  int Msum = 0;

#define MFMA_ __builtin_amdgcn_mfma_f32_16x16x32_bf16
#define STORE_MT(mt, x0, x1, x2, x3)                                   \
  {                                                                    \
    short4v sv = {(short)f2bf(x0), (short)f2bf(x1), (short)f2bf(x2),   \
                  (short)f2bf(x3)};                                    \
    *(short4v*)&vlds[LSTR * b + 16 * (mt) + 4 * q] = sv;               \
  }

  for (int c8 = 0; c8 < Lc / 8; ++c8) {
    const int cbase = c8 * 8;
    const int m0 = mp[cbase + q];
    const int m1 = mp[cbase + 4 + q];
    const unsigned long long bal0 = __ballot(m0 != 0);
    const unsigned long long bal1 = __ballot(m1 != 0);
#pragma unroll
    for (int u = 0; u < 8; ++u) {
      const int t = cbase + u;
      const unsigned mm =
          (unsigned)((u < 4 ? bal0 : bal1) >> (16 * (u & 3))) & 0xFFFFu;

      // rescale exponent from stale representative element (exact Msum)
      const int rep =
          __builtin_amdgcn_readfirstlane((int)(unsigned short)B0[0]);
      const unsigned e0 = ((unsigned)rep >> 7) & 0xFFu;
      const int d = (e0 == 0u) ? 0 : (int)e0 - 127;
      Msum += d;
      const float mdf = (float)(-d);

      float4 p0 = pf[u & 3][0], p1 = pf[u & 3][1], p2 = pf[u & 3][2],
             p3 = pf[u & 3][3];
      // issue next prefetch into the freed slot
      {
        const int tn = (t + 4 < Lc) ? (t + 4) : (Lc - 1);
#pragma unroll
        for (int mt = 0; mt < 4; ++mt)
          pf[u & 3][mt] =
              *(const float4*)(ep + (size_t)tn * NTAGS + 16 * mt);
      }

      // wrs[i,b] = exp(emit) * 2^-d, off the MFMA critical path
#define WRS(P, W0, W1, W2, W3)                          \
      const float W0 = exp2f(fmaf(P.x, LOG2E, mdf));    \
      const float W1 = exp2f(fmaf(P.y, LOG2E, mdf));    \
      const float W2 = exp2f(fmaf(P.z, LOG2E, mdf));    \
      const float W3 = exp2f(fmaf(P.w, LOG2E, mdf));
      WRS(p0, w00, w01, w02, w03)
      WRS(p1, w10, w11, w12, w13)
      WRS(p2, w20, w21, w22, w23)
      WRS(p3, w30, w31, w32, w33)

      f4 D0 = MFMA_(A00, B0, (f4){0.f, 0.f, 0.f, 0.f}, 0, 0, 0);
      D0 = MFMA_(A01, B1, D0, 0, 0, 0);
      f4 D1 = MFMA_(A10, B0, (f4){0.f, 0.f, 0.f, 0.f}, 0, 0, 0);
      D1 = MFMA_(A11, B1, D1, 0, 0, 0);
      f4 D2 = MFMA_(A20, B0, (f4){0.f, 0.f, 0.f, 0.f}, 0, 0, 0);
      D2 = MFMA_(A21, B1, D2, 0, 0, 0);
      f4 D3 = MFMA_(A30, B0, (f4){0.f, 0.f, 0.f, 0.f}, 0, 0, 0);
      D3 = MFMA_(A31, B1, D3, 0, 0, 0);

      if (mm == 0xFFFFu) {
        STORE_MT(0, D0[0] * w00, D0[1] * w01, D0[2] * w02, D0[3] * w03)
        STORE_MT(1, D1[0] * w10, D1[1] * w11, D1[2] * w12, D1[3] * w13)
        STORE_MT(2, D2[0] * w20, D2[1] * w21, D2[2] * w22, D2[3] * w23)
        STORE_MT(3, D3[0] * w30, D3[1] * w31, D3[2] * w32, D3[3] * w33)
      } else {
        // some columns masked out: v'[i,b] = sum_j v[j,b] (no trans, no emit)
        float cs = 0.f;
#pragma unroll
        for (int e = 0; e < 8; ++e) {
          cs += bf2f((unsigned short)B0[e]);
          cs += bf2f((unsigned short)B1[e]);
        }
        cs += __shfl_xor(cs, 16, 64);
        cs += __shfl_xor(cs, 32, 64);
        const float rs = __uint_as_float((unsigned)(127 - d) << 23);
        const float csr = cs * rs;
        const bool keep = ((mm >> b) & 1u) != 0u;
        STORE_MT(0, keep ? D0[0] * w00 : csr, keep ? D0[1] * w01 : csr,
                 keep ? D0[2] * w02 : csr, keep ? D0[3] * w03 : csr)
        STORE_MT(1, keep ? D1[0] * w10 : csr, keep ? D1[1] * w11 : csr,
                 keep ? D1[2] * w12 : csr, keep ? D1[3] * w13 : csr)
        STORE_MT(2, keep ? D2[0] * w20 : csr, keep ? D2[1] * w21 : csr,
                 keep ? D2[2] * w22 : csr, keep ? D2[3] * w23 : csr)
        STORE_MT(3, keep ? D3[0] * w30 : csr, keep ? D3[1] * w31 : csr,
                 keep ? D3[2] * w32 : csr, keep ? D3[3] * w33 : csr)
      }
      __builtin_amdgcn_wave_barrier();
      B0 = *(const short8*)&vlds[LSTR * b + 8 * q];
      B1 = *(const short8*)&vlds[LSTR * b + 32 + 8 * q];
    }
  }

  // ---- epilogue: logden_b = log(sum_j v[j,b]*exp(trans[STOP,j])) + Msum*ln2
  const float mf = (float)Msum;
  const float C = fmaf(mf, -2.1219444e-4f, mf * 0.693359375f);
  float dot = 0.f;
#pragma unroll
  for (int jj = 0; jj < 16; ++jj) {
    const int j = 16 * q + jj;
    dot += bf2f(vlds[LSTR * b + j]) * __expf(trans[STOP_T * NTAGS + j]);
  }
  dot += __shfl_xor(dot, 16, 64);
  dot += __shfl_xor(dot, 32, 64);
  if (lane < 16) den[bg] = __logf(dot) + C;
}

// ---------------------------------------------------------------------------
// Numerator score (exact, fully parallel): one wave per batch.
// ---------------------------------------------------------------------------
__global__ void crf_num(const float* __restrict__ inputs,
                        const int* __restrict__ tags,
                        const int* __restrict__ mask,
                        const float* __restrict__ trans,
                        float* __restrict__ num) {
  const int b = blockIdx.x;
  const int lane = threadIdx.x;
  const float* emit_base = inputs + (size_t)b * Lc * NTAGS;
  const int* tags_b = tags + b * Lc;
  const int* mask_b = mask + b * Lc;

  float sc = 0.0f;
  for (int l = lane; l < Lc; l += 64) {
    int tl = tags_b[l];
    float mfl = (float)mask_b[l];
    if (l < Lc - 1) {
      int tn = tags_b[l + 1];
      float mfn = (float)mask_b[l + 1];
      sc += trans[tn * NTAGS + tl] * mfn +
            emit_base[(size_t)l * NTAGS + tl] * mfl;
    } else {
      sc += trans[STOP_T * NTAGS + tl] +
            emit_base[(size_t)l * NTAGS + tl] * mfl;
    }
  }
  if (lane == 0) sc += trans[tags_b[0] * NTAGS + START_T];
  float score = wave_sum(sc);
  if (lane == 0) num[b] = score;
}

__global__ void crf_reduce(const float* __restrict__ num,
                           const float* __restrict__ den,
                           float* __restrict__ out) {
  const int lane = threadIdx.x;
  float s = 0.0f;
  for (int i = lane; i < Bc; i += 64) s += num[i] - den[i];
  s = wave_sum(s);
  if (lane == 0) out[0] = s;
}

}  // namespace

extern "C" void kernel_launch(void* const* d_in, const int* in_sizes, int n_in,
                              void* d_out, int out_size, void* d_ws,
                              size_t ws_size, hipStream_t stream) {
  const float* inputs = (const float*)d_in[0];
  const int* tags = (const int*)d_in[1];
  const int* mask = (const int*)d_in[2];
  const float* trans = (const float*)d_in[3];
  float* out = (float*)d_out;
  float* num = (float*)d_ws;        // [512]
  float* den = num + Bc;            // [512]

  crf_num<<<Bc, 64, 0, stream>>>(inputs, tags, mask, trans, num);
  crf_scan<<<Bc / 16, 64, 0, stream>>>(inputs, mask, trans, den);
  crf_reduce<<<1, 64, 0, stream>>>(num, den, out);
}